// Round 2
// baseline (808.427 us; speedup 1.0000x reference)
//
#include <hip/hip_runtime.h>
#include <hip/hip_bf16.h>

#define S_LEN 2048
#define BATCH 8
#define HID   1024
#define NP    3072      // permuted gate dim: i,g,o only (f is dead in reference)
#define MROWS 16384     // S*B

using bf16x8 = __attribute__((ext_vector_type(8))) short;
using f32x4  = __attribute__((ext_vector_type(4))) float;

__device__ __forceinline__ unsigned short f2b(float f) {
  unsigned int u = __builtin_bit_cast(unsigned int, f);
  u += 0x7fffu + ((u >> 16) & 1u);   // RNE
  return (unsigned short)(u >> 16);
}

__device__ __forceinline__ void load_lds16(const void* g, void* l) {
  __builtin_amdgcn_global_load_lds(
      (const __attribute__((address_space(1))) void*)g,
      (__attribute__((address_space(3))) void*)(unsigned int)(unsigned long long)l,
      16, 0, 0);
}

#define MEMFENCE asm volatile("" ::: "memory")
#define BARRIER  do { MEMFENCE; __builtin_amdgcn_s_barrier(); MEMFENCE; } while (0)

// ---- fp32 -> bf16 convert (vectorized float4 -> ushort4) ----
__global__ void cvt_f32_bf16(const float* __restrict__ in,
                             unsigned short* __restrict__ out, int n4) {
  int i = blockIdx.x * blockDim.x + threadIdx.x;
  if (i >= n4) return;
  const float4 v = reinterpret_cast<const float4*>(in)[i];
  ushort4 u;
  u.x = f2b(v.x); u.y = f2b(v.y); u.z = f2b(v.z); u.w = f2b(v.w);
  reinterpret_cast<ushort4*>(out)[i] = u;
}

// ---- weight permute+convert: Wp[n'][k], n' = chunk*48 + gate3*16 + hl ----
__global__ void permute_w(const float* __restrict__ W,
                          unsigned short* __restrict__ Wp, int K) {
  long i = ((long)blockIdx.x * blockDim.x + threadIdx.x) * 4;
  int np = (int)(i / K);
  if (np >= NP) return;
  int k0 = (int)(i % K);
  int chunk = np / 48, rem = np % 48;
  int g3 = rem >> 4, hl = rem & 15;
  int og = (g3 == 0) ? 0 : (g3 == 1) ? 2 : 3;
  int n  = og * 1024 + chunk * 16 + hl;
  const float4 v = *reinterpret_cast<const float4*>(W + (long)n * K + k0);
  ushort4 u;
  u.x = f2b(v.x); u.y = f2b(v.y); u.z = f2b(v.z); u.w = f2b(v.w);
  *reinterpret_cast<ushort4*>(Wp + i) = u;
}

__global__ void permute_b(const float* __restrict__ b, float* __restrict__ bp) {
  int np = blockIdx.x * blockDim.x + threadIdx.x;
  if (np >= NP) return;
  int chunk = np / 48, rem = np % 48;
  int g3 = rem >> 4, hl = rem & 15;
  int og = (g3 == 0) ? 0 : (g3 == 1) ? 2 : 3;
  bp[np] = b[og * 1024 + chunk * 16 + hl];
}

// ---- fused GEMM + gates, 8-phase pipelined.
//  C = A[M,K] * Wp[NP,K]^T.  Block tile 128x384, BK=64, 512 thr (8 waves 2Mx4N).
//  Wave tile 64x96 = 4 m-frags x 6 n-frags (2 h-chunks x {i,g,o}).
//  LDS: 4 half-buffers x 32KB (A 64x64 @0, B 192x64 @8192). Prefetch depth 2
//  K-tiles, steady-state vmcnt(8) once per K-tile, raw s_barrier, setprio. ----
template <int MODE>  // 0: layer0 (bf16 out), 1: layer1 (fp32 out to d_out)
__global__ void __launch_bounds__(512, 2)
lstm_gemm(const unsigned short* __restrict__ A,
          const unsigned short* __restrict__ WpF,
          const unsigned short* __restrict__ WpB,
          const float* __restrict__ bpF, const float* __restrict__ bpB,
          int K,
          unsigned short* __restrict__ out_bf, float* __restrict__ out_f,
          float* __restrict__ hn, float* __restrict__ cn) {
  __shared__ __align__(16) char lds[131072];

  const int dir = blockIdx.z;
  const unsigned short* __restrict__ Wp = dir ? WpB : WpF;
  const float* __restrict__ bp = dir ? bpB : bpF;
  const int bm = blockIdx.y;   // 128-row band of A
  const int bn = blockIdx.x;   // 384-col band of Wp (8 h-chunks)

  const int tid  = threadIdx.x;
  const int wid  = tid >> 6;
  const int lane = tid & 63;
  const int wm   = wid >> 2;   // 0..1
  const int wn   = wid & 3;    // 0..3

  const int  nt = K >> 6;
  const long K2 = (long)K * 2;

  // ---- staging constants (linear LDS dest, pre-swizzled global source) ----
  const int srow  = tid >> 3;                             // 0..63 within region
  const int scolb = (((tid & 7) ^ (srow & 7)) << 4);      // swizzled col byte
  const char* Asrc = (const char*)A  + ((long)bm * 128 + srow) * K2 + scolb;
  const char* Bsrc = (const char*)Wp + ((long)bn * 384 + srow) * K2 + scolb;
  char* ldsw = lds + wid * 1024;

  // ---- compute-side constants (swizzled ds_read; row&7 == lane&7) ----
  const int co0 = (((lane >> 4) << 4)) ^ ((lane & 7) << 4);
  const int co1 = (64 + ((lane >> 4) << 4)) ^ ((lane & 7) << 4);
  const int arow_off  = (lane & 15) * 128;
  const int bbase_off = 8192 + (wn & 1) * 12288 + (lane & 15) * 128;

  f32x4 acc[4][6];
  const f32x4 zero = {0.f, 0.f, 0.f, 0.f};
#pragma unroll
  for (int i = 0; i < 4; ++i)
#pragma unroll
    for (int j = 0; j < 6; ++j) acc[i][j] = zero;

  auto STAGE = [&](int s) {   // stage half-tile s (4 x global_load_lds / thread)
    if (s < 2 * nt) {
      const long off = (long)(s >> 1) * 128;   // K-tile byte offset
      const long h   = (long)(s & 1);
      char* d = ldsw + (s & 3) * 32768;
      load_lds16(Asrc + h * 64 * K2 + off,            d);
      load_lds16(Bsrc + (h * 192      ) * K2 + off,   d + 8192);
      load_lds16(Bsrc + (h * 192 +  64) * K2 + off,   d + 16384);
      load_lds16(Bsrc + (h * 192 + 128) * K2 + off,   d + 24576);
    }
  };

  // prologue: tiles 0 and 1 in flight; wait for tile 0 (halves 0,1)
  STAGE(0); STAGE(1); STAGE(2); STAGE(3);
  asm volatile("s_waitcnt vmcnt(8)" ::: "memory");
  BARRIER;

#define MFMA_ROW(mf, areg)                                                   \
  do {                                                                       \
    __builtin_amdgcn_s_setprio(1);                                           \
    _Pragma("unroll")                                                        \
    for (int nf = 0; nf < 6; ++nf) {                                         \
      acc[mf][nf] = __builtin_amdgcn_mfma_f32_16x16x32_bf16(                 \
          areg[0], b0[nf], acc[mf][nf], 0, 0, 0);                            \
      acc[mf][nf] = __builtin_amdgcn_mfma_f32_16x16x32_bf16(                 \
          areg[1], b1[nf], acc[mf][nf], 0, 0, 0);                            \
    }                                                                        \
    __builtin_amdgcn_s_setprio(0);                                           \
  } while (0)

  for (int t = 0; t < nt; ++t) {
    const char* bufA = lds + ((2 * t + wm)        & 3) * 32768 + arow_off;
    const char* bufB = lds + ((2 * t + (wn >> 1)) & 3) * 32768 + bbase_off;

    bf16x8 b0[6], b1[6], a0[2], a1[2], a2[2], a3[2];

    // ---- phase 0: read all B frags + A mf0; MFMA mf0 ----
#pragma unroll
    for (int nf = 0; nf < 6; ++nf) {
      b0[nf] = *(const bf16x8*)(bufB + nf * 2048 + co0);
      b1[nf] = *(const bf16x8*)(bufB + nf * 2048 + co1);
    }
    a0[0] = *(const bf16x8*)(bufA + co0);
    a0[1] = *(const bf16x8*)(bufA + co1);
    BARRIER;
    asm volatile("s_waitcnt lgkmcnt(0)" ::: "memory");
    MFMA_ROW(0, a0);
    BARRIER;

    // ---- phase 1: read A mf1..mf3; MFMA mf1 (full lgkm drain -> all tile-t
    //      LDS reads complete before the phase-end barrier; required before
    //      phase 2's STAGE overwrites buffer (2t)&3) ----
    a1[0] = *(const bf16x8*)(bufA + 2048 + co0);
    a1[1] = *(const bf16x8*)(bufA + 2048 + co1);
    a2[0] = *(const bf16x8*)(bufA + 4096 + co0);
    a2[1] = *(const bf16x8*)(bufA + 4096 + co1);
    a3[0] = *(const bf16x8*)(bufA + 6144 + co0);
    a3[1] = *(const bf16x8*)(bufA + 6144 + co1);
    BARRIER;
    asm volatile("s_waitcnt lgkmcnt(0)" ::: "memory");
    MFMA_ROW(1, a1);
    BARRIER;

    // ---- phase 2: stage tile t+2 first half; MFMA mf2 ----
    STAGE(2 * t + 4);
    BARRIER;
    MFMA_ROW(2, a2);
    BARRIER;

    // ---- phase 3: stage tile t+2 second half; MFMA mf3; counted vmcnt ----
    STAGE(2 * t + 5);
    BARRIER;
    MFMA_ROW(3, a3);
    if (t < nt - 2) { asm volatile("s_waitcnt vmcnt(8)" ::: "memory"); }
    else            { asm volatile("s_waitcnt vmcnt(0)" ::: "memory"); }
    BARRIER;
  }
#undef MFMA_ROW

  // ---- epilogue: gates -> h (and h_n/c_n rows) ----
  const int col    = lane & 15;
  const int rbase  = (lane >> 4) * 4;
  const int chunk0 = bn * 8 + wn * 2;
  const int Lidx   = MODE * 2 + dir;

#pragma unroll
  for (int hg = 0; hg < 2; ++hg) {
    const int chunk  = chunk0 + hg;
    const int h      = chunk * 16 + col;
    const int outcol = dir * HID + h;
    const float bi = bp[chunk * 48 + col];
    const float bg = bp[chunk * 48 + 16 + col];
    const float bo = bp[chunk * 48 + 32 + col];
#pragma unroll
    for (int mf = 0; mf < 4; ++mf) {
#pragma unroll
      for (int r = 0; r < 4; ++r) {
        const int m = bm * 128 + wm * 64 + mf * 16 + rbase + r;
        const float iv = acc[mf][hg * 3 + 0][r] + bi;
        const float gv = acc[mf][hg * 3 + 1][r] + bg;
        const float ov = acc[mf][hg * 3 + 2][r] + bo;
        const float is = 1.f / (1.f + __expf(-iv));
        const float gt = tanhf(gv);
        const float os = 1.f / (1.f + __expf(-ov));
        const float c  = is * gt;
        const float hv = os * tanhf(c);
        if (MODE == 0) {
          out_bf[(long)m * 2048 + outcol] = f2b(hv);
        } else {
          out_f[(long)m * 2048 + outcol] = hv;
        }
        const bool wst = (dir == 0) ? (m >= (S_LEN - 1) * BATCH) : (m < BATCH);
        if (wst) {
          const int b = (dir == 0) ? (m - (S_LEN - 1) * BATCH) : m;
          hn[((long)Lidx * BATCH + b) * HID + h] = hv;
          cn[((long)Lidx * BATCH + b) * HID + h] = c;
        }
      }
    }
  }
}

extern "C" void kernel_launch(void* const* d_in, const int* in_sizes, int n_in,
                              void* d_out, int out_size, void* d_ws, size_t ws_size,
                              hipStream_t stream) {
  const float* x    = (const float*)d_in[0];
  const float* W_f0 = (const float*)d_in[1];
  const float* b_f0 = (const float*)d_in[2];
  const float* W_b0 = (const float*)d_in[3];
  const float* b_b0 = (const float*)d_in[4];
  const float* W_f1 = (const float*)d_in[5];
  const float* b_f1 = (const float*)d_in[6];
  const float* W_b1 = (const float*)d_in[7];
  const float* b_b1 = (const float*)d_in[8];

  float* out = (float*)d_out;
  float* hn  = out + (long)MROWS * 2048;
  float* cn  = hn + 4 * BATCH * HID;

  unsigned short* x_bf  = (unsigned short*)d_ws;
  unsigned short* out1  = x_bf + (long)MROWS * 1024;
  unsigned short* wp_f0 = out1 + (long)MROWS * 2048;
  unsigned short* wp_b0 = wp_f0 + (long)NP * 1024;
  unsigned short* wp_f1 = wp_b0 + (long)NP * 1024;
  unsigned short* wp_b1 = wp_f1 + (long)NP * 2048;
  float* bp_f0 = (float*)(wp_b1 + (long)NP * 2048);
  float* bp_b0 = bp_f0 + NP;
  float* bp_f1 = bp_b0 + NP;
  float* bp_b1 = bp_f1 + NP;

  cvt_f32_bf16<<<16384, 256, 0, stream>>>(x, x_bf, MROWS * 1024 / 4);
  permute_w<<<3072, 256, 0, stream>>>(W_f0, wp_f0, 1024);
  permute_w<<<3072, 256, 0, stream>>>(W_b0, wp_b0, 1024);
  permute_w<<<6144, 256, 0, stream>>>(W_f1, wp_f1, 2048);
  permute_w<<<6144, 256, 0, stream>>>(W_b1, wp_b1, 2048);
  permute_b<<<12, 256, 0, stream>>>(b_f0, bp_f0);
  permute_b<<<12, 256, 0, stream>>>(b_b0, bp_b0);
  permute_b<<<12, 256, 0, stream>>>(b_f1, bp_f1);
  permute_b<<<12, 256, 0, stream>>>(b_b1, bp_b1);

  dim3 grid(NP / 384, MROWS / 128, 2);
  lstm_gemm<0><<<grid, 512, 0, stream>>>(x_bf, wp_f0, wp_b0, bp_f0, bp_b0, 1024,
                                         out1, nullptr, hn, cn);
  lstm_gemm<1><<<grid, 512, 0, stream>>>(out1, wp_f1, wp_b1, bp_f1, bp_b1, 2048,
                                         nullptr, out, hn, cn);
}

// Round 3
// 656.958 us; speedup vs baseline: 1.2306x; 1.2306x over previous
//
#include <hip/hip_runtime.h>
#include <hip/hip_bf16.h>

#define S_LEN 2048
#define BATCH 8
#define HID   1024
#define NP    3072      // permuted gate dim: i,g,o only (f is dead in reference)
#define MROWS 16384     // S*B

using bf16x8 = __attribute__((ext_vector_type(8))) short;
using f32x4  = __attribute__((ext_vector_type(4))) float;

__device__ __forceinline__ unsigned short f2b(float f) {
  unsigned int u = __builtin_bit_cast(unsigned int, f);
  u += 0x7fffu + ((u >> 16) & 1u);   // RNE
  return (unsigned short)(u >> 16);
}

__device__ __forceinline__ void load_lds16(const void* g, void* l) {
  __builtin_amdgcn_global_load_lds(
      (const __attribute__((address_space(1))) void*)g,
      (__attribute__((address_space(3))) void*)(unsigned int)(unsigned long long)l,
      16, 0, 0);
}

#define MEMFENCE asm volatile("" ::: "memory")
#define BARRIER  do { MEMFENCE; __builtin_amdgcn_s_barrier(); MEMFENCE; } while (0)

// ---- fp32 -> bf16 convert (vectorized float4 -> ushort4) ----
__global__ void cvt_f32_bf16(const float* __restrict__ in,
                             unsigned short* __restrict__ out, int n4) {
  int i = blockIdx.x * blockDim.x + threadIdx.x;
  if (i >= n4) return;
  const float4 v = reinterpret_cast<const float4*>(in)[i];
  ushort4 u;
  u.x = f2b(v.x); u.y = f2b(v.y); u.z = f2b(v.z); u.w = f2b(v.w);
  reinterpret_cast<ushort4*>(out)[i] = u;
}

// ---- weight permute+convert: Wp[n'][k], n' = chunk*48 + gate3*16 + hl ----
__global__ void permute_w(const float* __restrict__ W,
                          unsigned short* __restrict__ Wp, int K) {
  long i = ((long)blockIdx.x * blockDim.x + threadIdx.x) * 4;
  int np = (int)(i / K);
  if (np >= NP) return;
  int k0 = (int)(i % K);
  int chunk = np / 48, rem = np % 48;
  int g3 = rem >> 4, hl = rem & 15;
  int og = (g3 == 0) ? 0 : (g3 == 1) ? 2 : 3;
  int n  = og * 1024 + chunk * 16 + hl;
  const float4 v = *reinterpret_cast<const float4*>(W + (long)n * K + k0);
  ushort4 u;
  u.x = f2b(v.x); u.y = f2b(v.y); u.z = f2b(v.z); u.w = f2b(v.w);
  *reinterpret_cast<ushort4*>(Wp + i) = u;
}

__global__ void permute_b(const float* __restrict__ b, float* __restrict__ bp) {
  int np = blockIdx.x * blockDim.x + threadIdx.x;
  if (np >= NP) return;
  int chunk = np / 48, rem = np % 48;
  int g3 = rem >> 4, hl = rem & 15;
  int og = (g3 == 0) ? 0 : (g3 == 1) ? 2 : 3;
  bp[np] = b[og * 1024 + chunk * 16 + hl];
}

// ---- fused GEMM + gates, single-phase double-buffered.
//  C = A[M,K] * Wp[NP,K]^T.  Block tile 128x192, BK=64, 256 thr (4 waves 2Mx2N).
//  Wave tile 64x96 = 4 m-frags x 6 n-frags (2 h-chunks x {i,g,o}) = 48 MFMA/tile.
//  LDS: 2 buffers x 40KB (A 128x64 @0, B 192x64 @16384) = 80KB -> 2 blocks/CU.
//  K-loop: STAGE(t+1) early -> 20 ds_reads -> 48 MFMA -> vmcnt(0) -> 1 barrier.
template <int MODE>  // 0: layer0 (bf16 out), 1: layer1 (fp32 out to d_out)
__global__ void __launch_bounds__(256, 2)
lstm_gemm(const unsigned short* __restrict__ A,
          const unsigned short* __restrict__ WpF,
          const unsigned short* __restrict__ WpB,
          const float* __restrict__ bpF, const float* __restrict__ bpB,
          int K,
          unsigned short* __restrict__ out_bf, float* __restrict__ out_f,
          float* __restrict__ hn, float* __restrict__ cn) {
  __shared__ __align__(16) char lds[81920];

  const int dir = blockIdx.z;
  const unsigned short* __restrict__ Wp = dir ? WpB : WpF;
  const float* __restrict__ bp = dir ? bpB : bpF;
  const int bm = blockIdx.y;   // 128-row band of A
  const int bn = blockIdx.x;   // 192-col band of Wp (4 h-chunks)

  const int tid  = threadIdx.x;
  const int wid  = tid >> 6;
  const int lane = tid & 63;
  const int wm   = wid >> 1;   // 0..1
  const int wn   = wid & 1;    // 0..1

  const int  nt = K >> 6;
  const long K2 = (long)K * 2;

  // ---- staging constants (linear LDS dest, pre-swizzled global source).
  //  Slot = 8 rows x 128B = 1KB, written by one global_load_lds of one wave.
  //  LDS (row, c16) holds global (row, c16 ^ (row&7)).
  const int rlane = lane >> 3;                       // row within slot 0..7
  const int cb    = (((lane & 7) ^ rlane) << 4);     // pre-swizzled col byte
  const char* Asrc = (const char*)A  + ((long)bm * 128 + rlane) * K2 + cb;
  const char* Bsrc = (const char*)Wp + ((long)bn * 192 + rlane) * K2 + cb;

  // ---- compute-side constants (swizzled ds_read) ----
  const int l15 = lane & 15;
  const int hi  = lane >> 4;                  // 0..3
  const int c0  = ((hi ^ (l15 & 7)) << 4);    // kh0 chunk; kh1 = c0 ^ 64
  const int aro = (wm * 64 + l15) * 128;            // + mf*2048
  const int bro = 16384 + (wn * 96 + l15) * 128;    // + nf*2048

  f32x4 acc[4][6];
  const f32x4 zero = {0.f, 0.f, 0.f, 0.f};
#pragma unroll
  for (int i = 0; i < 4; ++i)
#pragma unroll
    for (int j = 0; j < 6; ++j) acc[i][j] = zero;

  auto STAGE = [&](int t) {   // 10 x global_load_lds per thread
    if (t >= nt) return;
    char* d = lds + (t & 1) * 40960;
    const long off = (long)t * 128;   // 64 bf16 = 128 B per K-tile
#pragma unroll
    for (int s = 0; s < 4; ++s) {
      const int slot = s * 4 + wid;   // 0..15 -> A rows slot*8..slot*8+7
      load_lds16(Asrc + (long)(slot * 8) * K2 + off, d + slot * 1024);
    }
#pragma unroll
    for (int s = 0; s < 6; ++s) {
      const int slot = s * 4 + wid;   // 0..23 -> B rows slot*8..slot*8+7
      load_lds16(Bsrc + (long)(slot * 8) * K2 + off, d + 16384 + slot * 1024);
    }
  };

  STAGE(0);
  asm volatile("s_waitcnt vmcnt(0)" ::: "memory");
  BARRIER;

  for (int t = 0; t < nt; ++t) {
    STAGE(t + 1);   // issue early; latency hidden under reads + MFMA below

    const char* buf = lds + (t & 1) * 40960;
    bf16x8 a[4][2], b[6][2];
#pragma unroll
    for (int nf = 0; nf < 6; ++nf) {
      b[nf][0] = *(const bf16x8*)(buf + bro + nf * 2048 + c0);
      b[nf][1] = *(const bf16x8*)(buf + bro + nf * 2048 + (c0 ^ 64));
    }
#pragma unroll
    for (int mf = 0; mf < 4; ++mf) {
      a[mf][0] = *(const bf16x8*)(buf + aro + mf * 2048 + c0);
      a[mf][1] = *(const bf16x8*)(buf + aro + mf * 2048 + (c0 ^ 64));
    }

    __builtin_amdgcn_s_setprio(1);
#pragma unroll
    for (int mf = 0; mf < 4; ++mf)
#pragma unroll
      for (int nf = 0; nf < 6; ++nf) {
        acc[mf][nf] = __builtin_amdgcn_mfma_f32_16x16x32_bf16(
            a[mf][0], b[nf][0], acc[mf][nf], 0, 0, 0);
        acc[mf][nf] = __builtin_amdgcn_mfma_f32_16x16x32_bf16(
            a[mf][1], b[nf][1], acc[mf][nf], 0, 0, 0);
      }
    __builtin_amdgcn_s_setprio(0);

    // all iter-t ds_reads completed (consumed by MFMAs above); drain stage
    // loads so buf[(t+1)&1] is fully written before next iter reads it.
    asm volatile("s_waitcnt vmcnt(0)" ::: "memory");
    BARRIER;
  }

  // ---- epilogue: gates -> h (and h_n/c_n rows) ----
  const int col    = l15;
  const int rbase  = hi * 4;
  const int chunk0 = bn * 4 + wn * 2;
  const int Lidx   = MODE * 2 + dir;

#pragma unroll
  for (int hg = 0; hg < 2; ++hg) {
    const int chunk  = chunk0 + hg;
    const int h      = chunk * 16 + col;
    const int outcol = dir * HID + h;
    const float bi = bp[chunk * 48 + col];
    const float bg = bp[chunk * 48 + 16 + col];
    const float bo = bp[chunk * 48 + 32 + col];
#pragma unroll
    for (int mf = 0; mf < 4; ++mf) {
#pragma unroll
      for (int r = 0; r < 4; ++r) {
        const int m = bm * 128 + wm * 64 + mf * 16 + rbase + r;
        const float iv = acc[mf][hg * 3 + 0][r] + bi;
        const float gv = acc[mf][hg * 3 + 1][r] + bg;
        const float ov = acc[mf][hg * 3 + 2][r] + bo;
        const float is = 1.f / (1.f + __expf(-iv));
        const float gt = tanhf(gv);
        const float os = 1.f / (1.f + __expf(-ov));
        const float c  = is * gt;
        const float hv = os * tanhf(c);
        if (MODE == 0) {
          out_bf[(long)m * 2048 + outcol] = f2b(hv);
        } else {
          out_f[(long)m * 2048 + outcol] = hv;
        }
        const bool wst = (dir == 0) ? (m >= (S_LEN - 1) * BATCH) : (m < BATCH);
        if (wst) {
          const int b = (dir == 0) ? (m - (S_LEN - 1) * BATCH) : m;
          hn[((long)Lidx * BATCH + b) * HID + h] = hv;
          cn[((long)Lidx * BATCH + b) * HID + h] = c;
        }
      }
    }
  }
}

extern "C" void kernel_launch(void* const* d_in, const int* in_sizes, int n_in,
                              void* d_out, int out_size, void* d_ws, size_t ws_size,
                              hipStream_t stream) {
  const float* x    = (const float*)d_in[0];
  const float* W_f0 = (const float*)d_in[1];
  const float* b_f0 = (const float*)d_in[2];
  const float* W_b0 = (const float*)d_in[3];
  const float* b_b0 = (const float*)d_in[4];
  const float* W_f1 = (const float*)d_in[5];
  const float* b_f1 = (const float*)d_in[6];
  const float* W_b1 = (const float*)d_in[7];
  const float* b_b1 = (const float*)d_in[8];

  float* out = (float*)d_out;
  float* hn  = out + (long)MROWS * 2048;
  float* cn  = hn + 4 * BATCH * HID;

  unsigned short* x_bf  = (unsigned short*)d_ws;
  unsigned short* out1  = x_bf + (long)MROWS * 1024;
  unsigned short* wp_f0 = out1 + (long)MROWS * 2048;
  unsigned short* wp_b0 = wp_f0 + (long)NP * 1024;
  unsigned short* wp_f1 = wp_b0 + (long)NP * 1024;
  unsigned short* wp_b1 = wp_f1 + (long)NP * 2048;
  float* bp_f0 = (float*)(wp_b1 + (long)NP * 2048);
  float* bp_b0 = bp_f0 + NP;
  float* bp_f1 = bp_b0 + NP;
  float* bp_b1 = bp_f1 + NP;

  cvt_f32_bf16<<<16384, 256, 0, stream>>>(x, x_bf, MROWS * 1024 / 4);
  permute_w<<<3072, 256, 0, stream>>>(W_f0, wp_f0, 1024);
  permute_w<<<3072, 256, 0, stream>>>(W_b0, wp_b0, 1024);
  permute_w<<<6144, 256, 0, stream>>>(W_f1, wp_f1, 2048);
  permute_w<<<6144, 256, 0, stream>>>(W_b1, wp_b1, 2048);
  permute_b<<<12, 256, 0, stream>>>(b_f0, bp_f0);
  permute_b<<<12, 256, 0, stream>>>(b_b0, bp_b0);
  permute_b<<<12, 256, 0, stream>>>(b_f1, bp_f1);
  permute_b<<<12, 256, 0, stream>>>(b_b1, bp_b1);

  dim3 grid(NP / 192, MROWS / 128, 2);
  lstm_gemm<0><<<grid, 256, 0, stream>>>(x_bf, wp_f0, wp_b0, bp_f0, bp_b0, 1024,
                                         out1, nullptr, hn, cn);
  lstm_gemm<1><<<grid, 256, 0, stream>>>(out1, wp_f1, wp_b1, bp_f1, bp_b1, 2048,
                                         nullptr, out, hn, cn);
}